// Round 2
// baseline (8448.943 us; speedup 1.0000x reference)
//
#include <hip/hip_runtime.h>
#include <hip/hip_bf16.h>

#define VOCAB 32000
#define HID 512
#define BATCH 256
#define SEQ 128
#define NL 5
#define BH (BATCH*HID)      // 131072
#define G4H (4*HID)         // 2048
#define NW (NL*G4H*HID)     // 5,242,880 elements per weight tensor

typedef __attribute__((ext_vector_type(8))) short short8;
typedef __attribute__((ext_vector_type(4))) float float4v;

__device__ __forceinline__ float sigmoid_f(float x) {
    return 1.f / (1.f + __expf(-x));
}
__device__ __forceinline__ float tanh_f(float x) {
    float ax = fabsf(x);
    float e = __expf(2.f * ax);       // overflow -> inf -> t = 1 (safe)
    float t = 1.f - 2.f / (e + 1.f);
    return copysignf(t, x);
}

__device__ __forceinline__ short bf16bits(float f) {
    union { __hip_bfloat16 b; short s; } u;
    u.b = __float2bfloat16(f);
    return u.s;
}

// load 8 contiguous elements as a bf16 MFMA fragment
__device__ __forceinline__ short8 load8(const __hip_bfloat16* p) {
    return *(const short8*)p;
}
__device__ __forceinline__ short8 load8(const float* p) {
    float4v lo = *(const float4v*)p;
    float4v hi = *(const float4v*)(p + 4);
    short8 r;
    r[0] = bf16bits(lo[0]); r[1] = bf16bits(lo[1]);
    r[2] = bf16bits(lo[2]); r[3] = bf16bits(lo[3]);
    r[4] = bf16bits(hi[0]); r[5] = bf16bits(hi[1]);
    r[6] = bf16bits(hi[2]); r[7] = bf16bits(hi[3]);
    return r;
}

// ---------------------------------------------------------------------------
// init: h0 -> parity-1 fp32 h buffer, c0 -> fp32 c ws
// ---------------------------------------------------------------------------
__global__ void init_state_k(const float* __restrict__ h0,
                             const float* __restrict__ c0,
                             float* __restrict__ hbuf1,
                             float* __restrict__ cws) {
    int i = blockIdx.x * 256 + threadIdx.x;   // grid covers NL*BH exactly
    hbuf1[i] = h0[i];
    cws[i] = c0[i];
}

// ---------------------------------------------------------------------------
// fp32 -> bf16 weight conversion (8 elements/thread)
// ---------------------------------------------------------------------------
__global__ void conv_w_k(const float* __restrict__ src,
                         __hip_bfloat16* __restrict__ dst) {
    int g = blockIdx.x * 256 + threadIdx.x;   // grid covers n/8 exactly
    const float* p = src + (size_t)g * 8;
    short8 r = load8(p);
    *(short8*)(dst + (size_t)g * 8) = r;
}

// ---------------------------------------------------------------------------
// one wavefront step: cells (l, t=s-l) for l in [l0, l0+ncells)
// grid: ncells*32 blocks of 512 threads.
// block tile: 128 rows (m) x 32 hidden-cols (jj) x 4 gates.
// Each lane holds i,f,g,o for its (m,jj) in registers -> register epilogue.
// h double-buffered fp32 by t-parity; c fp32 RMW by owning lane only.
// WT = __hip_bfloat16 (pre-converted) or float (on-the-fly cvt fallback).
// ---------------------------------------------------------------------------
template <typename WT>
__global__ __launch_bounds__(512) void lstm_cell_k(
    const int* __restrict__ x,
    const float* __restrict__ emb,
    const WT* __restrict__ W_ih,
    const WT* __restrict__ W_hh,
    const float* __restrict__ b_ih,
    const float* __restrict__ b_hh,
    float* __restrict__ hbuf,
    float* __restrict__ cws,
    int s, int l0)
{
    const int cell = blockIdx.x >> 5;
    const int l = l0 + cell;
    const int t = s - l;
    const int blk = blockIdx.x & 31;
    const int mblock = blk >> 4;          // 0..1
    const int jblock = blk & 15;          // 0..15
    const int tid = threadIdx.x;
    const int wave = tid >> 6;            // 0..7
    const int lane = tid & 63;
    const int quad = lane >> 4;
    const int l16 = lane & 15;
    const int ms = wave & 3;
    const int jjh = wave >> 2;

    const int mwave = mblock * 128 + ms * 32;
    const int jj = jblock * 32 + jjh * 16 + l16;     // 0..511

    const WT* wih_l = W_ih + (size_t)l * G4H * HID;
    const WT* whh_l = W_hh + (size_t)l * G4H * HID;

    const WT* browi[4];
    const WT* browh[4];
#pragma unroll
    for (int g = 0; g < 4; ++g) {
        int ncol = g * HID + jj;
        browi[g] = wih_l + (size_t)ncol * HID;
        browh[g] = whh_l + (size_t)ncol * HID;
    }

    const int pin = t & 1;
    const int pprev = pin ^ 1;
    const float* hbase = hbuf + ((size_t)pprev * NL + l) * BH;
    const float* inbase =
        (l == 0) ? (const float*)nullptr
                 : hbuf + ((size_t)pin * NL + (l - 1)) * BH;

    const float* arow[2];
    const float* hrow[2];
#pragma unroll
    for (int mi = 0; mi < 2; ++mi) {
        int m = mwave + mi * 16 + l16;
        if (l == 0) {
            int tok = x[t * BATCH + m];   // seq row r = t*B+m -> emb[x_flat[r]]
            arow[mi] = emb + (size_t)tok * HID;
        } else {
            arow[mi] = inbase + (size_t)m * HID;
        }
        hrow[mi] = hbase + (size_t)m * HID;
    }

    float4v acc[2][4];
#pragma unroll
    for (int mi = 0; mi < 2; ++mi)
#pragma unroll
        for (int g = 0; g < 4; ++g)
            acc[mi][g] = (float4v){0.f, 0.f, 0.f, 0.f};

    // input GEMM: X @ W_ih^T
    for (int k = 0; k < HID; k += 32) {
        short8 a0 = load8(arow[0] + k + quad * 8);
        short8 a1 = load8(arow[1] + k + quad * 8);
#pragma unroll
        for (int g = 0; g < 4; ++g) {
            short8 b = load8(browi[g] + k + quad * 8);
            acc[0][g] = __builtin_amdgcn_mfma_f32_16x16x32_bf16(a0, b, acc[0][g], 0, 0, 0);
            acc[1][g] = __builtin_amdgcn_mfma_f32_16x16x32_bf16(a1, b, acc[1][g], 0, 0, 0);
        }
    }
    // recurrent GEMM: H @ W_hh^T
    for (int k = 0; k < HID; k += 32) {
        short8 a0 = load8(hrow[0] + k + quad * 8);
        short8 a1 = load8(hrow[1] + k + quad * 8);
#pragma unroll
        for (int g = 0; g < 4; ++g) {
            short8 b = load8(browh[g] + k + quad * 8);
            acc[0][g] = __builtin_amdgcn_mfma_f32_16x16x32_bf16(a0, b, acc[0][g], 0, 0, 0);
            acc[1][g] = __builtin_amdgcn_mfma_f32_16x16x32_bf16(a1, b, acc[1][g], 0, 0, 0);
        }
    }

    float bias[4];
#pragma unroll
    for (int g = 0; g < 4; ++g) {
        int ncol = g * HID + jj;
        bias[g] = b_ih[l * G4H + ncol] + b_hh[l * G4H + ncol];
    }

    float* cl = cws + (size_t)l * BH;
    float* hout = hbuf + ((size_t)pin * NL + l) * BH;

#pragma unroll
    for (int mi = 0; mi < 2; ++mi) {
#pragma unroll
        for (int r = 0; r < 4; ++r) {
            int m = mwave + mi * 16 + quad * 4 + r;
            float iv = sigmoid_f(acc[mi][0][r] + bias[0]);
            float fv = sigmoid_f(acc[mi][1][r] + bias[1]);
            float gv = tanh_f(acc[mi][2][r] + bias[2]);
            float ov = sigmoid_f(acc[mi][3][r] + bias[3]);
            size_t idx = (size_t)m * HID + jj;
            float cnew = fv * cl[idx] + iv * gv;
            cl[idx] = cnew;
            hout[idx] = ov * tanh_f(cnew);
        }
    }
}

// ---------------------------------------------------------------------------
// output projection: out(256 x 32000) = h_final @ W_out^T + b_out   (fp32 I/O)
// grid: 500 blocks (250 n-blocks x 2 m-blocks) of 512 threads, 128x128 tiles
// ---------------------------------------------------------------------------
__global__ __launch_bounds__(512) void out_gemm_k(
    const float* __restrict__ hbuf,
    const float* __restrict__ W_out,
    const float* __restrict__ b_out,
    float* __restrict__ out)
{
    const int nb = blockIdx.x >> 1;       // 0..249
    const int mblock = blockIdx.x & 1;
    const int tid = threadIdx.x;
    const int wave = tid >> 6;
    const int lane = tid & 63;
    const int quad = lane >> 4;
    const int l16 = lane & 15;
    const int ms = wave & 3;
    const int nh = wave >> 2;             // 0..1

    // final h: t=127 (parity 1), layer NL-1
    const float* hfin = hbuf + ((size_t)1 * NL + (NL - 1)) * BH;

    const int mwave = mblock * 128 + ms * 32;

    const float* arow[2];
#pragma unroll
    for (int mi = 0; mi < 2; ++mi) {
        int m = mwave + mi * 16 + l16;
        arow[mi] = hfin + (size_t)m * HID;
    }
    const float* brow[4];
    int ncols[4];
#pragma unroll
    for (int q = 0; q < 4; ++q) {
        int ncol = nb * 128 + (nh + 2 * q) * 16 + l16;
        ncols[q] = ncol;
        brow[q] = W_out + (size_t)ncol * HID;
    }

    float4v acc[2][4];
#pragma unroll
    for (int mi = 0; mi < 2; ++mi)
#pragma unroll
        for (int q = 0; q < 4; ++q)
            acc[mi][q] = (float4v){0.f, 0.f, 0.f, 0.f};

    for (int k = 0; k < HID; k += 32) {
        short8 a0 = load8(arow[0] + k + quad * 8);
        short8 a1 = load8(arow[1] + k + quad * 8);
#pragma unroll
        for (int q = 0; q < 4; ++q) {
            short8 b = load8(brow[q] + k + quad * 8);
            acc[0][q] = __builtin_amdgcn_mfma_f32_16x16x32_bf16(a0, b, acc[0][q], 0, 0, 0);
            acc[1][q] = __builtin_amdgcn_mfma_f32_16x16x32_bf16(a1, b, acc[1][q], 0, 0, 0);
        }
    }

#pragma unroll
    for (int q = 0; q < 4; ++q) {
        float bo = b_out[ncols[q]];
#pragma unroll
        for (int mi = 0; mi < 2; ++mi) {
#pragma unroll
            for (int r = 0; r < 4; ++r) {
                int m = mwave + mi * 16 + quad * 4 + r;
                out[(size_t)m * VOCAB + ncols[q]] = acc[mi][q][r] + bo;
            }
        }
    }
}

extern "C" void kernel_launch(void* const* d_in, const int* in_sizes, int n_in,
                              void* d_out, int out_size, void* d_ws, size_t ws_size,
                              hipStream_t stream) {
    const int* x        = (const int*)d_in[0];
    const float* h0     = (const float*)d_in[1];
    const float* c0     = (const float*)d_in[2];
    const float* emb    = (const float*)d_in[3];
    const float* W_ih   = (const float*)d_in[4];
    const float* W_hh   = (const float*)d_in[5];
    const float* b_ih   = (const float*)d_in[6];
    const float* b_hh   = (const float*)d_in[7];
    const float* W_out  = (const float*)d_in[8];
    const float* b_out  = (const float*)d_in[9];
    float* out          = (float*)d_out;

    // ws layout: h double-buffer (2,NL,B,H) fp32 | c (NL,B,H) fp32 | bf16 weights
    const size_t H_ELEMS = (size_t)2 * NL * BH;
    const size_t C_ELEMS = (size_t)NL * BH;
    const size_t NEED_BASE = (H_ELEMS + C_ELEMS) * sizeof(float);          // 7.86 MB
    const size_t NEED_FULL = NEED_BASE + (size_t)2 * NW * sizeof(__hip_bfloat16); // 28.8 MB

    float* hbuf = (float*)d_ws;
    float* cws  = hbuf + H_ELEMS;
    __hip_bfloat16* wb_ih = (__hip_bfloat16*)(cws + C_ELEMS);
    __hip_bfloat16* wb_hh = wb_ih + NW;

    const bool preconv = (ws_size >= NEED_FULL);

    // init parity-1 h from h0, c from c0 (ws is re-poisoned before every call)
    init_state_k<<<(NL * BH) / 256, 256, 0, stream>>>(h0, c0, hbuf + (size_t)NL * BH, cws);

    if (preconv) {
        conv_w_k<<<NW / 8 / 256, 256, 0, stream>>>(W_ih, wb_ih);
        conv_w_k<<<NW / 8 / 256, 256, 0, stream>>>(W_hh, wb_hh);
    }

    // wavefront over s = t + l
    for (int s = 0; s < SEQ + NL - 1; ++s) {
        int l0 = s - (SEQ - 1); if (l0 < 0) l0 = 0;
        int l1 = (s < NL - 1) ? s : (NL - 1);
        int ncells = l1 - l0 + 1;
        if (preconv) {
            lstm_cell_k<__hip_bfloat16><<<ncells * 32, 512, 0, stream>>>(
                x, emb, wb_ih, wb_hh, b_ih, b_hh, hbuf, cws, s, l0);
        } else {
            lstm_cell_k<float><<<ncells * 32, 512, 0, stream>>>(
                x, emb, W_ih, W_hh, b_ih, b_hh, hbuf, cws, s, l0);
        }
    }

    out_gemm_k<<<500, 512, 0, stream>>>(hbuf, W_out, b_out, out);
}

// Round 3
// 4035.663 us; speedup vs baseline: 2.0936x; 2.0936x over previous
//
#include <hip/hip_runtime.h>
#include <hip/hip_bf16.h>

#define VOCAB 32000
#define HID 512
#define BATCH 256
#define SEQ 128
#define NL 5
#define BH (BATCH*HID)      // 131072
#define G4H (4*HID)         // 2048
#define NBLK 160            // 5 layers x 32 column-slices, 1 block/CU

typedef __attribute__((ext_vector_type(8))) short short8;
typedef __attribute__((ext_vector_type(4))) float float4v;

__device__ __forceinline__ float sigmoid_f(float x) {
    return 1.f / (1.f + __expf(-x));
}
__device__ __forceinline__ float tanh_f(float x) {
    float ax = fabsf(x);
    float e = __expf(2.f * ax);
    float t = 1.f - 2.f / (e + 1.f);
    return copysignf(t, x);
}
__device__ __forceinline__ short bf16bits(float f) {
    union { __hip_bfloat16 b; short s; } u;
    u.b = __float2bfloat16(f);
    return u.s;
}
__device__ __forceinline__ short8 load8f(const float* p) {   // fp32 -> bf16 frag
    float4v lo = *(const float4v*)p;
    float4v hi = *(const float4v*)(p + 4);
    short8 r;
    r[0] = bf16bits(lo[0]); r[1] = bf16bits(lo[1]);
    r[2] = bf16bits(lo[2]); r[3] = bf16bits(lo[3]);
    r[4] = bf16bits(hi[0]); r[5] = bf16bits(hi[1]);
    r[6] = bf16bits(hi[2]); r[7] = bf16bits(hi[3]);
    return r;
}
__device__ __forceinline__ short8 load8b(const __hip_bfloat16* p) {
    return *(const short8*)p;
}

// ---------------------------------------------------------------------------
// init: h0 fp32 -> parity-1 bf16 h buffer; zero the done counters
// ---------------------------------------------------------------------------
__global__ void init_state_k(const float* __restrict__ h0,
                             __hip_bfloat16* __restrict__ hbuf1,
                             int* __restrict__ done) {
    int i = blockIdx.x * 256 + threadIdx.x;   // grid covers NL*BH exactly
    hbuf1[i] = __float2bfloat16(h0[i]);
    if (blockIdx.x == 0 && threadIdx.x < NL) done[threadIdx.x * 64] = 0;
}

// ---------------------------------------------------------------------------
// persistent wavefront LSTM.
// block = (layer l, hidden-col slice j of 16 cols). 1024 threads = 16 waves;
// wave w owns m-tile rows [w*16, w*16+16). LDS holds the block's weight slice
// (2 GEMMs x 4 gates x 16 cols x 512 k) bf16 in MFMA-fragment order: 128 KB.
// c lives in registers. h exchanged via global bf16 parity double-buffer,
// ordered by per-layer monotonic counters (device-scope atomics).
// ---------------------------------------------------------------------------
__global__ __launch_bounds__(1024) void lstm_persist_k(
    const int* __restrict__ x,
    const float* __restrict__ emb,
    const float* __restrict__ W_ih,
    const float* __restrict__ W_hh,
    const float* __restrict__ b_ih,
    const float* __restrict__ b_hh,
    const float* __restrict__ c0,
    __hip_bfloat16* __restrict__ hbuf,
    int* __restrict__ done)
{
    __shared__ short lw[65536];               // 128 KB: 128 frags x 64 lanes x 8 bf16

    const int tid = threadIdx.x;
    // XCD clustering: blockIdx%8 = XCD (heuristic); pack layers onto adjacent XCDs
    const int xcd = blockIdx.x & 7;
    const int ixc = blockIdx.x >> 3;          // 0..19
    const int slot = xcd * 20 + ixc;          // 0..159, XCD-contiguous
    const int l = slot >> 5;                  // layer 0..4
    const int j = slot & 31;                  // col slice 0..31
    const int jbase = j << 4;

    const int wave = tid >> 6, lane = tid & 63;
    const int quad = lane >> 4, l16 = lane & 15;
    const int m16 = wave << 4;                // this wave's 16 batch rows

    const float* Wg[2] = { W_ih + (size_t)l * G4H * HID,
                           W_hh + (size_t)l * G4H * HID };

    // ---- stage weight slice into LDS in fragment order (coalesced reads) ----
    for (int e = tid; e < 8192; e += 1024) {
        int row = e >> 6;                     // 0..127: gemm*64 + g*16 + rl
        int kc  = (e & 63) << 3;              // k base, step 8
        int gemm = row >> 6, r2 = row & 63, g = r2 >> 4, rl = r2 & 15;
        const float* src = Wg[gemm] + (size_t)(g * HID + jbase + rl) * HID + kc;
        short8 v = load8f(src);
        int kt = kc >> 5, q = (kc >> 3) & 3;
        int fragslot = ((gemm * 4 + g) * 16 + kt) * 64 + (q * 16 + rl);
        *(short8*)&lw[(size_t)fragslot * 8] = v;
    }

    // ---- per-lane persistent state ----
    const int jj = jbase + l16;               // output hidden col of this lane
    float bias[4], c_r[4];
#pragma unroll
    for (int g = 0; g < 4; ++g)
        bias[g] = b_ih[l * G4H + g * HID + jj] + b_hh[l * G4H + g * HID + jj];
#pragma unroll
    for (int r = 0; r < 4; ++r)
        c_r[r] = c0[(size_t)l * BH + (size_t)(m16 + quad * 4 + r) * HID + jj];

    const short* lwb = lw + (size_t)lane * 8; // lane-fixed LDS base

    __syncthreads();                          // LDS weights ready

    for (int t = 0; t < SEQ; ++t) {
        // ---- wait for dependencies (one poller, then block-wide barrier) ----
        if (tid == 0) {
            if (l > 0) {
                int need = 32 * (t + 1);
                while (__hip_atomic_load(&done[(l - 1) * 64], __ATOMIC_RELAXED,
                                         __HIP_MEMORY_SCOPE_AGENT) < need)
                    __builtin_amdgcn_s_sleep(1);
            }
            if (t > 0) {
                int need = 32 * t;
                while (__hip_atomic_load(&done[l * 64], __ATOMIC_RELAXED,
                                         __HIP_MEMORY_SCOPE_AGENT) < need)
                    __builtin_amdgcn_s_sleep(1);
            }
            if (l < NL - 1 && t >= 2) {
                int need = 32 * (t - 1);
                while (__hip_atomic_load(&done[(l + 1) * 64], __ATOMIC_RELAXED,
                                         __HIP_MEMORY_SCOPE_AGENT) < need)
                    __builtin_amdgcn_s_sleep(1);
            }
            __builtin_amdgcn_fence(__ATOMIC_ACQUIRE, "agent");
        }
        __syncthreads();

        const int p = t & 1, pm1 = p ^ 1;
        const __hip_bfloat16* hprev =
            hbuf + ((size_t)pm1 * NL + l) * BH + (size_t)(m16 + l16) * HID;

        float4v acc[4];
#pragma unroll
        for (int g = 0; g < 4; ++g) acc[g] = (float4v){0.f, 0.f, 0.f, 0.f};

        // ---- GEMM 1: input @ W_ih^T ----
        if (l == 0) {
            int tok = x[t * BATCH + m16 + l16];
            const float* ar = emb + (size_t)tok * HID;
#pragma unroll 4
            for (int kt = 0; kt < 16; ++kt) {
                short8 a = load8f(ar + kt * 32 + quad * 8);
#pragma unroll
                for (int g = 0; g < 4; ++g) {
                    short8 b = *(const short8*)(lwb + (size_t)(g * 16 + kt) * 512);
                    acc[g] = __builtin_amdgcn_mfma_f32_16x16x32_bf16(a, b, acc[g], 0, 0, 0);
                }
            }
        } else {
            const __hip_bfloat16* ar =
                hbuf + ((size_t)p * NL + (l - 1)) * BH + (size_t)(m16 + l16) * HID;
#pragma unroll 4
            for (int kt = 0; kt < 16; ++kt) {
                short8 a = load8b(ar + kt * 32 + quad * 8);
#pragma unroll
                for (int g = 0; g < 4; ++g) {
                    short8 b = *(const short8*)(lwb + (size_t)(g * 16 + kt) * 512);
                    acc[g] = __builtin_amdgcn_mfma_f32_16x16x32_bf16(a, b, acc[g], 0, 0, 0);
                }
            }
        }
        // ---- GEMM 2: h_prev @ W_hh^T ----
#pragma unroll 4
        for (int kt = 0; kt < 16; ++kt) {
            short8 a = load8b(hprev + kt * 32 + quad * 8);
#pragma unroll
            for (int g = 0; g < 4; ++g) {
                short8 b = *(const short8*)(lwb + (size_t)((4 + g) * 16 + kt) * 512);
                acc[g] = __builtin_amdgcn_mfma_f32_16x16x32_bf16(a, b, acc[g], 0, 0, 0);
            }
        }

        // ---- epilogue: register c, write h slice ----
        __hip_bfloat16* hout = hbuf + ((size_t)p * NL + l) * BH;
#pragma unroll
        for (int r = 0; r < 4; ++r) {
            int m = m16 + quad * 4 + r;
            float iv = sigmoid_f(acc[0][r] + bias[0]);
            float fv = sigmoid_f(acc[1][r] + bias[1]);
            float gv = tanh_f(acc[2][r] + bias[2]);
            float ov = sigmoid_f(acc[3][r] + bias[3]);
            c_r[r] = fv * c_r[r] + iv * gv;
            hout[(size_t)m * HID + jj] = __float2bfloat16(ov * tanh_f(c_r[r]));
        }

        __syncthreads();   // drains all waves' h stores to L2 (vmcnt(0) before barrier)
        if (tid == 0)
            __hip_atomic_fetch_add(&done[l * 64], 1, __ATOMIC_RELEASE,
                                   __HIP_MEMORY_SCOPE_AGENT);
    }
}

// ---------------------------------------------------------------------------
// output projection: out(256 x 32000) = h_final @ W_out^T + b_out
// 500 blocks x 512 thr; block = 64 ncols x full M=256. A = bf16 h (L2-hot),
// B = fp32 W_out streamed from HBM. wave: n-tile = w&3, m-half = w>>2.
// ---------------------------------------------------------------------------
__global__ __launch_bounds__(512) void out_gemm_k(
    const __hip_bfloat16* __restrict__ hbuf,
    const float* __restrict__ W_out,
    const float* __restrict__ b_out,
    float* __restrict__ out)
{
    const int nb = blockIdx.x;
    const int tid = threadIdx.x;
    const int wave = tid >> 6, lane = tid & 63;
    const int quad = lane >> 4, l16 = lane & 15;
    const int nt = wave & 3, mh = wave >> 2;      // 4 n-tiles, 2 m-halves

    const __hip_bfloat16* hfin = hbuf + ((size_t)1 * NL + (NL - 1)) * BH;

    const int ncol = nb * 64 + nt * 16 + l16;
    const float* brow = W_out + (size_t)ncol * HID;

    const __hip_bfloat16* arow[8];
#pragma unroll
    for (int mt = 0; mt < 8; ++mt)
        arow[mt] = hfin + (size_t)(mh * 128 + mt * 16 + l16) * HID;

    float4v acc[8];
#pragma unroll
    for (int mt = 0; mt < 8; ++mt) acc[mt] = (float4v){0.f, 0.f, 0.f, 0.f};

#pragma unroll 2
    for (int kt = 0; kt < 16; ++kt) {
        short8 b = load8f(brow + kt * 32 + quad * 8);
#pragma unroll
        for (int mt = 0; mt < 8; ++mt) {
            short8 a = load8b(arow[mt] + kt * 32 + quad * 8);
            acc[mt] = __builtin_amdgcn_mfma_f32_16x16x32_bf16(a, b, acc[mt], 0, 0, 0);
        }
    }

    float bo = b_out[ncol];
#pragma unroll
    for (int mt = 0; mt < 8; ++mt) {
#pragma unroll
        for (int r = 0; r < 4; ++r) {
            int m = mh * 128 + mt * 16 + quad * 4 + r;
            out[(size_t)m * VOCAB + ncol] = acc[mt][r] + bo;
        }
    }
}

extern "C" void kernel_launch(void* const* d_in, const int* in_sizes, int n_in,
                              void* d_out, int out_size, void* d_ws, size_t ws_size,
                              hipStream_t stream) {
    const int* x        = (const int*)d_in[0];
    const float* h0     = (const float*)d_in[1];
    const float* c0     = (const float*)d_in[2];
    const float* emb    = (const float*)d_in[3];
    const float* W_ih   = (const float*)d_in[4];
    const float* W_hh   = (const float*)d_in[5];
    const float* b_ih   = (const float*)d_in[6];
    const float* b_hh   = (const float*)d_in[7];
    const float* W_out  = (const float*)d_in[8];
    const float* b_out  = (const float*)d_in[9];
    float* out          = (float*)d_out;

    // ws: h parity double-buffer (2,NL,B,H) bf16 | done counters (NL x 64 ints)
    __hip_bfloat16* hbuf = (__hip_bfloat16*)d_ws;
    int* done = (int*)((char*)d_ws + (size_t)2 * NL * BH * sizeof(__hip_bfloat16));

    init_state_k<<<(NL * BH) / 256, 256, 0, stream>>>(h0, hbuf + (size_t)NL * BH, done);

    lstm_persist_k<<<NBLK, 1024, 0, stream>>>(x, emb, W_ih, W_hh, b_ih, b_hh,
                                              c0, hbuf, done);

    out_gemm_k<<<VOCAB / 64, 512, 0, stream>>>(hbuf, W_out, b_out, out);
}

// Round 4
// 3646.934 us; speedup vs baseline: 2.3167x; 1.1066x over previous
//
#include <hip/hip_runtime.h>
#include <hip/hip_bf16.h>

#define VOCAB 32000
#define HID 512
#define BATCH 256
#define SEQ 128
#define NL 5
#define BH (BATCH*HID)      // 131072
#define G4H (4*HID)         // 2048
#define NBLK 160            // 5 layers x 32 column-slices, 1 block/CU

typedef __attribute__((ext_vector_type(8))) short short8;
typedef __attribute__((ext_vector_type(4))) float float4v;

__device__ __forceinline__ float sigmoid_f(float x) {
    return 1.f / (1.f + __expf(-x));
}
__device__ __forceinline__ float tanh_f(float x) {
    float ax = fabsf(x);
    float e = __expf(2.f * ax);
    float t = 1.f - 2.f / (e + 1.f);
    return copysignf(t, x);
}
__device__ __forceinline__ short bf16bits(float f) {
    union { __hip_bfloat16 b; short s; } u;
    u.b = __float2bfloat16(f);
    return u.s;
}
__device__ __forceinline__ short8 load8f(const float* p) {   // fp32 -> bf16 frag
    float4v lo = *(const float4v*)p;
    float4v hi = *(const float4v*)(p + 4);
    short8 r;
    r[0] = bf16bits(lo[0]); r[1] = bf16bits(lo[1]);
    r[2] = bf16bits(lo[2]); r[3] = bf16bits(lo[3]);
    r[4] = bf16bits(hi[0]); r[5] = bf16bits(hi[1]);
    r[6] = bf16bits(hi[2]); r[7] = bf16bits(hi[3]);
    return r;
}
__device__ __forceinline__ short8 load8b(const __hip_bfloat16* p) {
    return *(const short8*)p;
}
// coherent (agent-scope, LLC-direct) 16B fragment load as two u64 atomics
__device__ __forceinline__ short8 load8coh(const __hip_bfloat16* p) {
    union { unsigned long long q[2]; short8 s; } u;
    u.q[0] = __hip_atomic_load((const unsigned long long*)p,
                               __ATOMIC_RELAXED, __HIP_MEMORY_SCOPE_AGENT);
    u.q[1] = __hip_atomic_load((const unsigned long long*)(p + 4),
                               __ATOMIC_RELAXED, __HIP_MEMORY_SCOPE_AGENT);
    return u.s;
}

// h layout: slice-contiguous [p][l][j(32)][m(256)][c(16)] bf16
__device__ __forceinline__ size_t hidx(int p, int l, int j, int m, int c) {
    return ((((size_t)p * NL + l) * 32 + j) * 256 + m) * 16 + c;
}

// ---------------------------------------------------------------------------
// init: h0 fp32 -> parity-1 bf16 h buffer (slice layout); zero done counters
// ---------------------------------------------------------------------------
__global__ void init_state_k(const float* __restrict__ h0,
                             __hip_bfloat16* __restrict__ hbuf,
                             int* __restrict__ done) {
    int i = blockIdx.x * 256 + threadIdx.x;   // grid covers NL*BH exactly
    int l = i / BH, r = i % BH;
    int m = r >> 9, col = r & 511;
    hbuf[hidx(1, l, col >> 4, m, col & 15)] = __float2bfloat16(h0[i]);
    if (blockIdx.x == 0 && threadIdx.x < NL) done[threadIdx.x * 64] = 0;
}

// ---------------------------------------------------------------------------
// persistent wavefront LSTM. block = (layer l, 16-col slice j); 16 waves,
// wave w owns rows [16w,16w+16). Weights bf16 in LDS (128 KB, frag order).
// c in registers. h exchanged via relaxed agent-scope atomics (LLC-direct,
// NO per-step fences -> no L2 invalidate storm). Flags: monotonic counters.
// ---------------------------------------------------------------------------
__global__ __launch_bounds__(1024) void lstm_persist_k(
    const int* __restrict__ x,
    const float* __restrict__ emb,
    const float* __restrict__ W_ih,
    const float* __restrict__ W_hh,
    const float* __restrict__ b_ih,
    const float* __restrict__ b_hh,
    const float* __restrict__ c0,
    __hip_bfloat16* __restrict__ hbuf,
    int* __restrict__ done)
{
    __shared__ short lw[65536];               // 128 KB weight slice

    const int tid = threadIdx.x;
    const int xcd = blockIdx.x & 7;
    const int ixc = blockIdx.x >> 3;
    const int slot = xcd * 20 + ixc;          // XCD-contiguous slots
    const int l = slot >> 5;                  // layer 0..4
    const int j = slot & 31;                  // col slice 0..31
    const int jbase = j << 4;

    const int wave = tid >> 6, lane = tid & 63;
    const int quad = lane >> 4, l16 = lane & 15;
    const int m16 = wave << 4;

    const float* Wg[2] = { W_ih + (size_t)l * G4H * HID,
                           W_hh + (size_t)l * G4H * HID };

    // ---- stage weight slice into LDS in fragment order ----
    for (int e = tid; e < 8192; e += 1024) {
        int row = e >> 6;
        int kc  = (e & 63) << 3;
        int gemm = row >> 6, r2 = row & 63, g = r2 >> 4, rl = r2 & 15;
        const float* src = Wg[gemm] + (size_t)(g * HID + jbase + rl) * HID + kc;
        short8 v = load8f(src);
        int kt = kc >> 5, q = (kc >> 3) & 3;
        int fragslot = ((gemm * 4 + g) * 16 + kt) * 64 + (q * 16 + rl);
        *(short8*)&lw[(size_t)fragslot * 8] = v;
    }

    // ---- per-lane persistent state ----
    const int jj = jbase + l16;
    float bias[4], c_r[4];
#pragma unroll
    for (int g = 0; g < 4; ++g)
        bias[g] = b_ih[l * G4H + g * HID + jj] + b_hh[l * G4H + g * HID + jj];
#pragma unroll
    for (int r = 0; r < 4; ++r)
        c_r[r] = c0[(size_t)l * BH + (size_t)(m16 + quad * 4 + r) * HID + jj];

    const short* lwb = lw + (size_t)lane * 8;
    // within-slice offset of this lane's A-row piece: row (m16+l16), col (quad&1)*8
    const size_t aoff = (size_t)(m16 + l16) * 16 + (size_t)(quad & 1) * 8;
    const int shi = quad >> 1;                // slice parity from quad

    __syncthreads();

    for (int t = 0; t < SEQ; ++t) {
        // ---- dependency wait (tid0 polls, then barrier) ----
        if (tid == 0) {
            if (l > 0) {
                int need = 32 * (t + 1);
                while (__hip_atomic_load(&done[(l - 1) * 64], __ATOMIC_RELAXED,
                                         __HIP_MEMORY_SCOPE_AGENT) < need)
                    __builtin_amdgcn_s_sleep(1);
            }
            if (t > 0) {
                int need = 32 * t;
                while (__hip_atomic_load(&done[l * 64], __ATOMIC_RELAXED,
                                         __HIP_MEMORY_SCOPE_AGENT) < need)
                    __builtin_amdgcn_s_sleep(1);
            }
            if (l < NL - 1 && t >= 2) {
                int need = 32 * (t - 1);
                while (__hip_atomic_load(&done[(l + 1) * 64], __ATOMIC_RELAXED,
                                         __HIP_MEMORY_SCOPE_AGENT) < need)
                    __builtin_amdgcn_s_sleep(1);
            }
        }
        __syncthreads();

        const int p = t & 1, pm1 = p ^ 1;
        const __hip_bfloat16* hprev_b = hbuf + hidx(pm1, l, 0, 0, 0) + aoff;

        float4v acc[4];
#pragma unroll
        for (int g = 0; g < 4; ++g) acc[g] = (float4v){0.f, 0.f, 0.f, 0.f};

        if (l == 0) {
            int tok = x[t * BATCH + m16 + l16];
            const float* ar = emb + (size_t)tok * HID;
            // depth-2 rotate on hprev only (emb is normal cached loads)
            short8 ah[2];
            ah[0] = load8coh(hprev_b + (size_t)(0 + shi) * 4096);
            ah[1] = load8coh(hprev_b + (size_t)(2 + shi) * 4096);
#pragma unroll
            for (int kt = 0; kt < 16; ++kt) {
                short8 a_in = load8f(ar + kt * 32 + quad * 8);
                short8 a_h = ah[kt & 1];
                if (kt + 2 < 16)
                    ah[kt & 1] = load8coh(hprev_b + (size_t)(2 * (kt + 2) + shi) * 4096);
#pragma unroll
                for (int g = 0; g < 4; ++g) {
                    short8 b0 = *(const short8*)(lwb + (size_t)(g * 16 + kt) * 512);
                    short8 b1 = *(const short8*)(lwb + (size_t)((4 + g) * 16 + kt) * 512);
                    acc[g] = __builtin_amdgcn_mfma_f32_16x16x32_bf16(a_in, b0, acc[g], 0, 0, 0);
                    acc[g] = __builtin_amdgcn_mfma_f32_16x16x32_bf16(a_h,  b1, acc[g], 0, 0, 0);
                }
            }
        } else {
            const __hip_bfloat16* hin_b = hbuf + hidx(p, l - 1, 0, 0, 0) + aoff;
            short8 ai[2], ah[2];
            ai[0] = load8coh(hin_b   + (size_t)(0 + shi) * 4096);
            ah[0] = load8coh(hprev_b + (size_t)(0 + shi) * 4096);
            ai[1] = load8coh(hin_b   + (size_t)(2 + shi) * 4096);
            ah[1] = load8coh(hprev_b + (size_t)(2 + shi) * 4096);
#pragma unroll
            for (int kt = 0; kt < 16; ++kt) {
                short8 a_in = ai[kt & 1];
                short8 a_h  = ah[kt & 1];
                if (kt + 2 < 16) {
                    ai[kt & 1] = load8coh(hin_b   + (size_t)(2 * (kt + 2) + shi) * 4096);
                    ah[kt & 1] = load8coh(hprev_b + (size_t)(2 * (kt + 2) + shi) * 4096);
                }
#pragma unroll
                for (int g = 0; g < 4; ++g) {
                    short8 b0 = *(const short8*)(lwb + (size_t)(g * 16 + kt) * 512);
                    short8 b1 = *(const short8*)(lwb + (size_t)((4 + g) * 16 + kt) * 512);
                    acc[g] = __builtin_amdgcn_mfma_f32_16x16x32_bf16(a_in, b0, acc[g], 0, 0, 0);
                    acc[g] = __builtin_amdgcn_mfma_f32_16x16x32_bf16(a_h,  b1, acc[g], 0, 0, 0);
                }
            }
        }

        // ---- epilogue: register c; h out via relaxed agent 2B atomics ----
        short* hout = (short*)(hbuf + hidx(p, l, j, 0, 0));
#pragma unroll
        for (int r = 0; r < 4; ++r) {
            int m = m16 + quad * 4 + r;
            float iv = sigmoid_f(acc[0][r] + bias[0]);
            float fv = sigmoid_f(acc[1][r] + bias[1]);
            float gv = tanh_f(acc[2][r] + bias[2]);
            float ov = sigmoid_f(acc[3][r] + bias[3]);
            c_r[r] = fv * c_r[r] + iv * gv;
            __hip_atomic_store(&hout[m * 16 + l16], bf16bits(ov * tanh_f(c_r[r])),
                               __ATOMIC_RELAXED, __HIP_MEMORY_SCOPE_AGENT);
        }

        __syncthreads();   // all waves' stores drained (vmcnt) before flag
        if (tid == 0)
            __hip_atomic_fetch_add(&done[l * 64], 1, __ATOMIC_RELEASE,
                                   __HIP_MEMORY_SCOPE_AGENT);
    }
}

// ---------------------------------------------------------------------------
// output projection: out(256 x 32000) = h_final @ W_out^T + b_out
// 500 blocks x 512 thr; A = bf16 h (slice layout, cross-kernel visible),
// B = fp32 W_out streamed.
// ---------------------------------------------------------------------------
__global__ __launch_bounds__(512) void out_gemm_k(
    const __hip_bfloat16* __restrict__ hbuf,
    const float* __restrict__ W_out,
    const float* __restrict__ b_out,
    float* __restrict__ out)
{
    const int nb = blockIdx.x;
    const int tid = threadIdx.x;
    const int wave = tid >> 6, lane = tid & 63;
    const int quad = lane >> 4, l16 = lane & 15;
    const int nt = wave & 3, mh = wave >> 2;

    const __hip_bfloat16* hfin = hbuf + hidx(1, NL - 1, 0, 0, 0);
    const int shi = quad >> 1;
    const size_t coff = (size_t)(quad & 1) * 8;

    const int ncol = nb * 64 + nt * 16 + l16;
    const float* brow = W_out + (size_t)ncol * HID;

    float4v acc[8];
#pragma unroll
    for (int mt = 0; mt < 8; ++mt) acc[mt] = (float4v){0.f, 0.f, 0.f, 0.f};

#pragma unroll 2
    for (int kt = 0; kt < 16; ++kt) {
        short8 b = load8f(brow + kt * 32 + quad * 8);
        const __hip_bfloat16* abase =
            hfin + (size_t)(2 * kt + shi) * 4096 + coff;
#pragma unroll
        for (int mt = 0; mt < 8; ++mt) {
            short8 a = load8b(abase + (size_t)(mh * 128 + mt * 16 + l16) * 16);
            acc[mt] = __builtin_amdgcn_mfma_f32_16x16x32_bf16(a, b, acc[mt], 0, 0, 0);
        }
    }

    float bo = b_out[ncol];
#pragma unroll
    for (int mt = 0; mt < 8; ++mt) {
#pragma unroll
        for (int r = 0; r < 4; ++r) {
            int m = mh * 128 + mt * 16 + quad * 4 + r;
            out[(size_t)m * VOCAB + ncol] = acc[mt][r] + bo;
        }
    }
}

extern "C" void kernel_launch(void* const* d_in, const int* in_sizes, int n_in,
                              void* d_out, int out_size, void* d_ws, size_t ws_size,
                              hipStream_t stream) {
    const int* x        = (const int*)d_in[0];
    const float* h0     = (const float*)d_in[1];
    const float* c0     = (const float*)d_in[2];
    const float* emb    = (const float*)d_in[3];
    const float* W_ih   = (const float*)d_in[4];
    const float* W_hh   = (const float*)d_in[5];
    const float* b_ih   = (const float*)d_in[6];
    const float* b_hh   = (const float*)d_in[7];
    const float* W_out  = (const float*)d_in[8];
    const float* b_out  = (const float*)d_in[9];
    float* out          = (float*)d_out;

    // ws: h parity double-buffer (2,NL,B,H) bf16 slice layout | done counters
    __hip_bfloat16* hbuf = (__hip_bfloat16*)d_ws;
    int* done = (int*)((char*)d_ws + (size_t)2 * NL * BH * sizeof(__hip_bfloat16));

    init_state_k<<<(NL * BH) / 256, 256, 0, stream>>>(h0, hbuf, done);

    lstm_persist_k<<<NBLK, 1024, 0, stream>>>(x, emb, W_ih, W_hh, b_ih, b_hh,
                                              c0, hbuf, done);

    out_gemm_k<<<VOCAB / 64, 512, 0, stream>>>(hbuf, W_out, b_out, out);
}